// Round 2
// baseline (3525.961 us; speedup 1.0000x reference)
//
#include <hip/hip_runtime.h>

typedef _Float16 half8 __attribute__((ext_vector_type(8)));
typedef float f32x4 __attribute__((ext_vector_type(4)));
typedef unsigned long long u64x2 __attribute__((ext_vector_type(2)));

union H8U { unsigned long long u[2]; half8 v; };

__device__ __forceinline__ float fast_sigmoid(float v) {
  return 1.0f / (1.0f + __expf(-v));
}
__device__ __forceinline__ float fast_tanh(float v) {
  return 2.0f / (1.0f + __expf(-2.0f * v)) - 1.0f;
}

// ---------------------------------------------------------------------------
// prep: zero barrier flags; build frag-ordered f16 copies of W1, W2.
// Frag layout (B operand of mfma_f32_16x16x32_f16): flat index
// ((ct*8 + ks)*64 + lane)*8 + s holds W[k = ks*32+(lane>>4)*8+s][col = ct*16+(lane&15)]
// ---------------------------------------------------------------------------
__global__ void __launch_bounds__(256) prep_kernel(
    const float* __restrict__ W1, const float* __restrict__ W2,
    _Float16* __restrict__ W1f, _Float16* __restrict__ W2f,
    unsigned* __restrict__ flags)
{
  int idx = blockIdx.x * 256 + threadIdx.x;   // grid 512 -> 0..131071
  if (idx < 256)
    __hip_atomic_store(&flags[idx], 0u, __ATOMIC_RELAXED, __HIP_MEMORY_SCOPE_AGENT);
  int m  = idx >> 16;          // 0 -> W1, 1 -> W2
  int i2 = idx & 65535;
  int s = i2 & 7, lane = (i2 >> 3) & 63, ks = (i2 >> 9) & 7, ct = (i2 >> 12) & 15;
  int col = ct * 16 + (lane & 15);
  int k   = ks * 32 + (lane >> 4) * 8 + s;
  float v = (m == 0) ? W1[k * 256 + col] : W2[k * 256 + col];
  _Float16* dst = (m == 0) ? W1f : W2f;
  dst[i2] = (_Float16)v;
}

// ---------------------------------------------------------------------------
// Recurrence v2: 8 groups (32 rows each) paired; each WG serves 2 groups with
// one 64-gate-col weight slice (16 col-WGs per group). Grid = 4 pairs x 16 = 64.
// Pipeline per step: compute A | poll B(t-1) | compute B | poll A(t) — every
// poll has a full compute phase of slack, hiding barrier latency.
// ---------------------------------------------------------------------------
#define DO_PHASE(G, B0, XR, XB, GRP)                                           \
  {                                                                            \
    half8* Ag = (half8*)At[G];                                                 \
    /* stage h(t-1): agent-scope bypass loads (cross-WG exchange) */           \
    if (t > 0) {                                                               \
      const unsigned long long* hp = (const unsigned long long*)h_all +       \
          ((size_t)(t - 1) * 256 + (B0) + srow) * 64 + sseg * 8;               \
      H8U c0, c1, c2, c3;                                                      \
      c0.u[0] = __hip_atomic_load(hp + 0, __ATOMIC_RELAXED, __HIP_MEMORY_SCOPE_AGENT); \
      c0.u[1] = __hip_atomic_load(hp + 1, __ATOMIC_RELAXED, __HIP_MEMORY_SCOPE_AGENT); \
      c1.u[0] = __hip_atomic_load(hp + 2, __ATOMIC_RELAXED, __HIP_MEMORY_SCOPE_AGENT); \
      c1.u[1] = __hip_atomic_load(hp + 3, __ATOMIC_RELAXED, __HIP_MEMORY_SCOPE_AGENT); \
      c2.u[0] = __hip_atomic_load(hp + 4, __ATOMIC_RELAXED, __HIP_MEMORY_SCOPE_AGENT); \
      c2.u[1] = __hip_atomic_load(hp + 5, __ATOMIC_RELAXED, __HIP_MEMORY_SCOPE_AGENT); \
      c3.u[0] = __hip_atomic_load(hp + 6, __ATOMIC_RELAXED, __HIP_MEMORY_SCOPE_AGENT); \
      c3.u[1] = __hip_atomic_load(hp + 7, __ATOMIC_RELAXED, __HIP_MEMORY_SCOPE_AGENT); \
      int hb = (s_rt * 12 + 4 + sseg) * 64 + s_lrow;                           \
      Ag[hb + 0] = c0.v; Ag[hb + 16] = c1.v;                                   \
      Ag[hb + 32] = c2.v; Ag[hb + 48] = c3.v;                                  \
    } else {                                                                   \
      int hb = (s_rt * 12 + 4 + sseg) * 64 + s_lrow;                           \
      Ag[hb + 0] = zz.v; Ag[hb + 16] = zz.v;                                   \
      Ag[hb + 32] = zz.v; Ag[hb + 48] = zz.v;                                  \
    }                                                                          \
    /* stage x_t from prefetch regs */                                         \
    {                                                                          \
      half8 p0, p1;                                                            \
      p0[0] = (_Float16)XR[0].x; p0[1] = (_Float16)XR[0].y;                    \
      p0[2] = (_Float16)XR[0].z; p0[3] = (_Float16)XR[0].w;                    \
      p0[4] = (_Float16)XR[1].x; p0[5] = (_Float16)XR[1].y;                    \
      p0[6] = (_Float16)XR[1].z; p0[7] = (_Float16)XR[1].w;                    \
      p1[0] = (_Float16)XR[2].x; p1[1] = (_Float16)XR[2].y;                    \
      p1[2] = (_Float16)XR[2].z; p1[3] = (_Float16)XR[2].w;                    \
      p1[4] = (_Float16)XR[3].x; p1[5] = (_Float16)XR[3].y;                    \
      p1[6] = (_Float16)XR[3].z; p1[7] = (_Float16)XR[3].w;                    \
      int ksx = sseg >> 1, kgx = (sseg & 1) * 2;                               \
      int xb2 = (s_rt * 12 + ksx) * 64 + kgx * 16 + s_lrow;                    \
      Ag[xb2] = p0; Ag[xb2 + 16] = p1;                                         \
    }                                                                          \
    /* prefetch x_{t+1} (off critical path) */                                 \
    {                                                                          \
      int tn = (t + 1 < 512) ? (t + 1) : 511;                                  \
      XR[0] = XB[tn * 32 + 0]; XR[1] = XB[tn * 32 + 1];                        \
      XR[2] = XB[tn * 32 + 2]; XR[3] = XB[tn * 32 + 3];                        \
    }                                                                          \
    __syncthreads();                                                           \
    /* MFMA: [32x384]@[384x64]; per wave 2 col-tiles, K-chain 12 */            \
    {                                                                          \
      const half8* Ap  = (const half8*)At[G] + rt * 768 + lane;                \
      const half8* B0p = (const half8*)Wt + ct0 * 768 + lane;                  \
      const half8* B1p = (const half8*)Wt + ct1 * 768 + lane;                  \
      f32x4 a0 = {0.f, 0.f, 0.f, 0.f}, a1 = {0.f, 0.f, 0.f, 0.f};              \
      _Pragma("unroll")                                                        \
      for (int ks = 0; ks < 12; ++ks) {                                        \
        half8 av = Ap[ks * 64];                                                \
        a0 = __builtin_amdgcn_mfma_f32_16x16x32_f16(av, B0p[ks * 64], a0, 0, 0, 0); \
        a1 = __builtin_amdgcn_mfma_f32_16x16x32_f16(av, B1p[ks * 64], a1, 0, 0, 0); \
      }                                                                        \
      pre_s[G][prow + 0][pcol0] = a0[0]; pre_s[G][prow + 1][pcol0] = a0[1];    \
      pre_s[G][prow + 2][pcol0] = a0[2]; pre_s[G][prow + 3][pcol0] = a0[3];    \
      pre_s[G][prow + 0][pcol1] = a1[0]; pre_s[G][prow + 1][pcol1] = a1[1];    \
      pre_s[G][prow + 2][pcol1] = a1[2]; pre_s[G][prow + 3][pcol1] = a1[3];    \
    }                                                                          \
    __syncthreads();                                                           \
    /* elementwise LSTM update: (row, dim) and (row, dim+8) per thread */      \
    _Pragma("unroll")                                                          \
    for (int hh = 0; hh < 2; ++hh) {                                           \
      int dv = (tid & 7) + hh * 8;                                             \
      float ip = pre_s[G][srow][dv]      + bias_s[dv];                         \
      float fp = pre_s[G][srow][16 + dv] + bias_s[16 + dv];                    \
      float gp = pre_s[G][srow][32 + dv] + bias_s[32 + dv];                    \
      float op = pre_s[G][srow][48 + dv] + bias_s[48 + dv];                    \
      float iv = fast_sigmoid(ip);                                             \
      float fv = fast_sigmoid(fp);                                             \
      float gv = fast_tanh(gp);                                                \
      float ov = fast_sigmoid(op);                                             \
      float cv = fv * c_s[G][srow * 17 + dv] + iv * gv;                        \
      c_s[G][srow * 17 + dv] = cv;                                             \
      h_s[G][srow][dv] = (_Float16)(ov * fast_tanh(cv));                       \
    }                                                                          \
    __syncthreads();                                                           \
    /* wave0: coalesced 8B agent stores of h_t + release flag */               \
    if (wid == 0) {                                                            \
      int row = lane >> 1, part = lane & 1;                                    \
      u64x2 dv2 = ((const u64x2*)&h_s[G][0][0])[lane];                         \
      unsigned long long* hp = (unsigned long long*)h_all +                    \
          ((size_t)t * 256 + (B0) + row) * 64 + j * 4 + part * 2;              \
      __hip_atomic_store(hp + 0, dv2[0], __ATOMIC_RELAXED, __HIP_MEMORY_SCOPE_AGENT); \
      __hip_atomic_store(hp + 1, dv2[1], __ATOMIC_RELAXED, __HIP_MEMORY_SCOPE_AGENT); \
      if (lane == 0)                                                           \
        __hip_atomic_store(&flags[(GRP) * 16 + j], (unsigned)(t + 1),          \
                           __ATOMIC_RELEASE, __HIP_MEMORY_SCOPE_AGENT);        \
    }                                                                          \
  }

#define DO_POLL(GRP, TGT)                                                      \
  if (wid == 0) {                                                              \
    unsigned tgt = (unsigned)(TGT);                                            \
    int iters = 0;                                                             \
    while (true) {                                                             \
      unsigned v = (lane < 16)                                                 \
          ? __hip_atomic_load(&flags[(GRP) * 16 + lane], __ATOMIC_RELAXED,     \
                              __HIP_MEMORY_SCOPE_AGENT)                        \
          : tgt;                                                               \
      if (__ballot(v >= tgt) == ~0ull) break;                                  \
      if (++iters > (1 << 17)) break;   /* valve: garbage instead of hang */   \
      __builtin_amdgcn_s_sleep(1);                                             \
    }                                                                          \
  }                                                                            \
  __syncthreads();

__global__ void __launch_bounds__(256) lstm_rec_kernel(
    const float* __restrict__ x, const float* __restrict__ Wx,
    const float* __restrict__ Wh, const float* __restrict__ bias,
    _Float16* __restrict__ h_all, unsigned* __restrict__ flags)
{
  __shared__ __align__(16) _Float16 Wt[24576];      // 48 KB [4ct][12ks][64][8]
  __shared__ __align__(16) _Float16 At[2][12288];   // 2 x 24 KB
  __shared__ float pre_s[2][32][68];                // padded: no 8-way diag conflicts
  __shared__ float c_s[2][32 * 17];
  __shared__ __align__(16) _Float16 h_s[2][32][16];
  __shared__ float bias_s[64];

  const int tid = threadIdx.x;
  const int p = (blockIdx.x & 7) >> 1;                         // pair 0..3
  const int j = ((blockIdx.x & 1) << 3) | (blockIdx.x >> 3);   // col-WG 0..15
  const int ga = 2 * p, gb = 2 * p + 1;
  const int b0a = ga * 32, b0b = gb * 32;

  // ---- one-time: weight slice (64 gate-cols c = q*16+d -> gc = q*256+j*16+d)
  for (int idx = tid; idx < 384 * 64; idx += 256) {
    int k = idx >> 6, c = idx & 63;
    int q = c >> 4, d = c & 15;
    int gc = q * 256 + j * 16 + d;
    float v = (k < 128) ? Wx[k * 1024 + gc] : Wh[(k - 128) * 1024 + gc];
    int ks = k >> 5, kg = (k >> 3) & 3, s = k & 7;
    Wt[(((q * 12 + ks) * 64) + kg * 16 + d) * 8 + s] = (_Float16)v;
  }
  if (tid < 64) {
    int q = tid >> 4, d = tid & 15;
    bias_s[tid] = bias[q * 256 + j * 16 + d];
  }
  for (int i = tid; i < 2 * 32 * 17; i += 256) ((float*)c_s)[i] = 0.f;
  __syncthreads();

  const int lane = tid & 63, wid = tid >> 6;
  const int rt = wid & 1, ct0 = wid >> 1, ct1 = ct0 + 2;   // wave -> (rt, 2 cts)
  const int prow = rt * 16 + ((lane >> 4) << 2);
  const int pcol0 = ct0 * 16 + (lane & 15);
  const int pcol1 = ct1 * 16 + (lane & 15);

  const int srow = tid >> 3, sseg = tid & 7;               // staging: 32 x 8
  const int s_rt = srow >> 4, s_lrow = srow & 15;

  const float4* xbA = (const float4*)x + (size_t)(b0a + srow) * 16384 + sseg * 4;
  const float4* xbB = (const float4*)x + (size_t)(b0b + srow) * 16384 + sseg * 4;
  float4 xA[4], xB[4];
  xA[0] = xbA[0]; xA[1] = xbA[1]; xA[2] = xbA[2]; xA[3] = xbA[3];
  xB[0] = xbB[0]; xB[1] = xbB[1]; xB[2] = xbB[2]; xB[3] = xbB[3];

  H8U zz; zz.u[0] = 0ull; zz.u[1] = 0ull;

  for (int t = 0; t < 512; ++t) {
    DO_PHASE(0, b0a, xA, xbA, ga);   // compute A(t), store h, flag ga = t+1
    DO_POLL(gb, t);                  // B(t-1) flags: a compute phase old -> hit
    DO_PHASE(1, b0b, xB, xbB, gb);   // compute B(t)
    DO_POLL(ga, t + 1);              // A(t) flags: a compute phase old -> hit
  }
}

// ---------------------------------------------------------------------------
// Head: per WG 64 rows of [T*B, H]; fused GEMM1->tanh->GEMM2->tanh->dot(W3).
// ---------------------------------------------------------------------------
__device__ __forceinline__ void head_gemm(const _Float16* __restrict__ A,
                                          const _Float16* __restrict__ Wf,
                                          const float* __restrict__ bvec,
                                          _Float16* __restrict__ Yd,
                                          int lane, int w)
{
  const half8* Af = (const half8*)A + w * 512 + lane;
  for (int ct = 0; ct < 16; ++ct) {
    const half8* Bf = (const half8*)Wf + ct * 512 + lane;
    f32x4 acc = {0.f, 0.f, 0.f, 0.f};
    #pragma unroll
    for (int ks = 0; ks < 8; ++ks)
      acc = __builtin_amdgcn_mfma_f32_16x16x32_f16(Af[ks * 64], Bf[ks * 64], acc, 0, 0, 0);
    int col = ct * 16 + (lane & 15);
    float bb = bvec[col];
    int ks2 = col >> 5, kg2 = (col >> 3) & 3, s2 = col & 7;
    #pragma unroll
    for (int r = 0; r < 4; ++r) {
      int row = w * 16 + ((lane >> 4) << 2) + r;
      float v = fast_tanh(acc[r] + bb);
      Yd[(((w * 8 + ks2) * 64) + kg2 * 16 + (row & 15)) * 8 + s2] = (_Float16)v;
    }
  }
}

__global__ void __launch_bounds__(256) head_kernel(
    const _Float16* __restrict__ h_all,
    const _Float16* __restrict__ W1f, const _Float16* __restrict__ W2f,
    const float* __restrict__ b1, const float* __restrict__ b2,
    const float* __restrict__ W3, const float* __restrict__ b3,
    float* __restrict__ out)
{
  __shared__ __align__(16) _Float16 A_s[16384];   // 32 KB
  __shared__ __align__(16) _Float16 Y_s[16384];   // 32 KB
  const int tid = threadIdx.x;
  const size_t r0 = (size_t)blockIdx.x * 64;

  {
    int row = tid >> 2, seg = tid & 3;
    int rtl = row >> 4, lrow = row & 15;
    const half8* hp = (const half8*)(h_all + (r0 + row) * 256 + seg * 64);
    #pragma unroll
    for (int i = 0; i < 8; ++i) {
      int k0 = seg * 64 + i * 8;
      int ks = k0 >> 5, kg = (k0 >> 3) & 3;
      ((half8*)A_s)[(rtl * 8 + ks) * 64 + kg * 16 + lrow] = hp[i];
    }
  }
  __syncthreads();

  const int lane = tid & 63, w = tid >> 6;
  head_gemm(A_s, W1f, b1, Y_s, lane, w);   // y1 = tanh(h @ W1 + b1)
  __syncthreads();
  head_gemm(Y_s, W2f, b2, A_s, lane, w);   // y2 = tanh(y1 @ W2 + b2)
  __syncthreads();

  {
    int row = tid >> 2, part = tid & 3;
    int rtl = row >> 4, lrow = row & 15;
    float p = 0.f;
    #pragma unroll
    for (int kk = 0; kk < 8; ++kk) {
      int k0 = part * 64 + kk * 8;
      int ks = k0 >> 5, kg = (k0 >> 3) & 3;
      half8 y = ((const half8*)A_s)[(rtl * 8 + ks) * 64 + kg * 16 + lrow];
      #pragma unroll
      for (int i = 0; i < 8; ++i) p += (float)y[i] * W3[k0 + i];
    }
    p += __shfl_xor(p, 1);
    p += __shfl_xor(p, 2);
    if (part == 0) {
      size_t r = r0 + row;                 // r = t*256 + b
      int tt = (int)(r >> 8), bb = (int)(r & 255);
      out[(size_t)bb * 512 + tt] = p + b3[0];
    }
  }
}

// ---------------------------------------------------------------------------
extern "C" void kernel_launch(void* const* d_in, const int* in_sizes, int n_in,
                              void* d_out, int out_size, void* d_ws, size_t ws_size,
                              hipStream_t stream)
{
  const float* x  = (const float*)d_in[0];
  const float* Wx = (const float*)d_in[1];
  const float* Wh = (const float*)d_in[2];
  const float* b  = (const float*)d_in[3];
  const float* W1 = (const float*)d_in[4];
  const float* b1 = (const float*)d_in[5];
  const float* W2 = (const float*)d_in[6];
  const float* b2 = (const float*)d_in[7];
  const float* W3 = (const float*)d_in[8];
  const float* b3 = (const float*)d_in[9];
  float* out = (float*)d_out;

  char* ws = (char*)d_ws;
  unsigned* flags  = (unsigned*)ws;                       // 256 u32 (pad to 4 KB)
  _Float16* W1f    = (_Float16*)(ws + 4096);              // 128 KB
  _Float16* W2f    = (_Float16*)(ws + 4096 + 131072);     // 128 KB
  _Float16* h_all  = (_Float16*)(ws + 4096 + 262144);     // [512][256][256] f16 = 64 MB
  if (ws_size < (size_t)4096 + 262144 + 67108864) return; // insufficient scratch

  hipLaunchKernelGGL(prep_kernel, dim3(512), dim3(256), 0, stream,
                     W1, W2, W1f, W2f, flags);
  hipLaunchKernelGGL(lstm_rec_kernel, dim3(64), dim3(256), 0, stream,
                     x, Wx, Wh, b, h_all, flags);
  hipLaunchKernelGGL(head_kernel, dim3(2048), dim3(256), 0, stream,
                     h_all, W1f, W2f, b1, b2, W3, b3, out);
}

// Round 3
// 1960.326 us; speedup vs baseline: 1.7987x; 1.7987x over previous
//
#include <hip/hip_runtime.h>

typedef _Float16 half8 __attribute__((ext_vector_type(8)));
typedef float f32x4 __attribute__((ext_vector_type(4)));

union H8U { unsigned long long u[2]; half8 v; };

__device__ __forceinline__ float fast_sigmoid(float v) {
  return 1.0f / (1.0f + __expf(-v));
}
__device__ __forceinline__ float fast_tanh(float v) {
  return 2.0f / (1.0f + __expf(-2.0f * v)) - 1.0f;
}

#define AL(p) __hip_atomic_load((p), __ATOMIC_RELAXED, __HIP_MEMORY_SCOPE_AGENT)

// ---------------------------------------------------------------------------
// prep: zero barrier flags; build frag-ordered f16 copies of W1, W2.
// Frag layout (B operand of mfma_f32_16x16x32_f16): flat index
// ((ct*8 + ks)*64 + lane)*8 + s holds W[k = ks*32+(lane>>4)*8+s][col = ct*16+(lane&15)]
// ---------------------------------------------------------------------------
__global__ void __launch_bounds__(256) prep_kernel(
    const float* __restrict__ W1, const float* __restrict__ W2,
    _Float16* __restrict__ W1f, _Float16* __restrict__ W2f,
    unsigned* __restrict__ flags)
{
  int idx = blockIdx.x * 256 + threadIdx.x;   // grid 512 -> 0..131071
  if (idx < 256)
    __hip_atomic_store(&flags[idx], 0u, __ATOMIC_RELAXED, __HIP_MEMORY_SCOPE_AGENT);
  int m  = idx >> 16;          // 0 -> W1, 1 -> W2
  int i2 = idx & 65535;
  int s = i2 & 7, lane = (i2 >> 3) & 63, ks = (i2 >> 9) & 7, ct = (i2 >> 12) & 15;
  int col = ct * 16 + (lane & 15);
  int k   = ks * 32 + (lane >> 4) * 8 + s;
  float v = (m == 0) ? W1[k * 256 + col] : W2[k * 256 + col];
  _Float16* dst = (m == 0) ? W1f : W2f;
  dst[i2] = (_Float16)v;
}

// ---------------------------------------------------------------------------
// Recurrence v3: 8 groups (32 rows) x 8 col-WGs (128 gate-cols, K=384 fused
// x@Wx + h@Wh). ONE barrier round per step, 8 participants. Weight B-frags
// live in VGPRs (loop-invariant); x-part MFMA for step t+1 computed at the
// tail of step t (no h dependency) to fill the flag-propagation window.
// ---------------------------------------------------------------------------
__global__ void __launch_bounds__(256, 1) lstm_rec_kernel(
    const float* __restrict__ x, const float* __restrict__ Wx,
    const float* __restrict__ Wh, const float* __restrict__ bias,
    _Float16* __restrict__ h_all, unsigned* __restrict__ flags)
{
  __shared__ __align__(16) _Float16 Wt[8 * 12 * 64 * 8];   // 96 KB [ct][ks][lane][8]
  __shared__ __align__(16) _Float16 At[2 * 12 * 64 * 8];   // 24 KB [rt][ks][lane][8]
  __shared__ float pre_s[32][132];                         // 16.9 KB
  __shared__ float c_s[32][33];                            // 4.2 KB
  __shared__ __align__(16) _Float16 h_s[32][32];           // 2 KB
  __shared__ float bias_s[128];

  const int tid = threadIdx.x;
  const int g  = blockIdx.x & 7;    // group (8 WGs of a group land on one XCD)
  const int j  = blockIdx.x >> 3;   // col-owner 0..7 -> gate-cols q*256+j*32+[0,32)
  const int b0 = g * 32;

  // ---- one-time: weight slice 384 x 128 as f16 B-frags
  for (int idx = tid; idx < 384 * 128; idx += 256) {
    int k = idx >> 7, c = idx & 127;
    int q = c >> 5, d = c & 31;
    int gc = q * 256 + j * 32 + d;
    float v = (k < 128) ? Wx[k * 1024 + gc] : Wh[(k - 128) * 1024 + gc];
    int ct = c >> 4, lcol = c & 15;
    int ks = k >> 5, kg = (k >> 3) & 3, s = k & 7;
    Wt[(((ct * 12 + ks) * 64) + kg * 16 + lcol) * 8 + s] = (_Float16)v;
  }
  if (tid < 128) {
    int q = tid >> 5, d = tid & 31;
    bias_s[tid] = bias[q * 256 + j * 32 + d];
  }
  for (int i = tid; i < 32 * 33; i += 256) ((float*)c_s)[i] = 0.f;

  const int lane = tid & 63, wid = tid >> 6;
  const int rt = wid & 1;              // 16-row block
  const int c4 = (wid >> 1) * 4;       // 4 col-tiles per wave
  const int prow = rt * 16 + ((lane >> 4) << 2);
  const int pc = lane & 15;

  const int srow = tid >> 3, sseg = tid & 7;   // staging: 32 rows x 8 segs
  const int s_rt = srow >> 4, s_lrow = srow & 15;

  const half8* Ap = (const half8*)At + rt * 768 + lane;

  const float4* xb = (const float4*)x + (size_t)(b0 + srow) * 16384 + sseg * 4;
  float4 XR[4];
  XR[0] = xb[0]; XR[1] = xb[1]; XR[2] = xb[2]; XR[3] = xb[3];

  __syncthreads();   // Wt / bias / c_s ready

  // ---- hoist all 48 B-frags (4 ct x 12 ks) into VGPRs — loop-invariant
  half8 Bv[48];
  {
    const half8* Bb = (const half8*)Wt + c4 * 768 + lane;
    #pragma unroll
    for (int i = 0; i < 48; ++i) Bv[i] = Bb[(i >> 3) * 768 + (i & 7)];
  }
  // Bv index for (ct_local, ks): ct_local*12 + ks ... but loaded as
  // (i>>3)*768 + (i&7): i = ct_local*8 + r covers ks 0..7 only. Redo properly:
  {
    const half8* Bb = (const half8*)Wt + c4 * 768 + lane;
    #pragma unroll
    for (int ct = 0; ct < 4; ++ct)
      #pragma unroll
      for (int ks = 0; ks < 12; ++ks)
        Bv[ct * 12 + ks] = Bb[ct * 768 + ks * 64];
  }

  f32x4 accx0, accx1, accx2, accx3;

  // ---- pre-loop: stage x(0), compute x-part acc, prefetch x(1)
  {
    half8 p0, p1;
    p0[0] = (_Float16)XR[0].x; p0[1] = (_Float16)XR[0].y;
    p0[2] = (_Float16)XR[0].z; p0[3] = (_Float16)XR[0].w;
    p0[4] = (_Float16)XR[1].x; p0[5] = (_Float16)XR[1].y;
    p0[6] = (_Float16)XR[1].z; p0[7] = (_Float16)XR[1].w;
    p1[0] = (_Float16)XR[2].x; p1[1] = (_Float16)XR[2].y;
    p1[2] = (_Float16)XR[2].z; p1[3] = (_Float16)XR[2].w;
    p1[4] = (_Float16)XR[3].x; p1[5] = (_Float16)XR[3].y;
    p1[6] = (_Float16)XR[3].z; p1[7] = (_Float16)XR[3].w;
    int xi = (s_rt * 12 + (sseg >> 1)) * 64 + ((sseg & 1) * 2) * 16 + s_lrow;
    ((half8*)At)[xi] = p0; ((half8*)At)[xi + 16] = p1;
  }
  __syncthreads();
  {
    accx0 = (f32x4){0.f, 0.f, 0.f, 0.f}; accx1 = accx0; accx2 = accx0; accx3 = accx0;
    #pragma unroll
    for (int ks = 0; ks < 4; ++ks) {
      half8 av = Ap[ks * 64];
      accx0 = __builtin_amdgcn_mfma_f32_16x16x32_f16(av, Bv[0 * 12 + ks], accx0, 0, 0, 0);
      accx1 = __builtin_amdgcn_mfma_f32_16x16x32_f16(av, Bv[1 * 12 + ks], accx1, 0, 0, 0);
      accx2 = __builtin_amdgcn_mfma_f32_16x16x32_f16(av, Bv[2 * 12 + ks], accx2, 0, 0, 0);
      accx3 = __builtin_amdgcn_mfma_f32_16x16x32_f16(av, Bv[3 * 12 + ks], accx3, 0, 0, 0);
    }
  }
  XR[0] = xb[32]; XR[1] = xb[33]; XR[2] = xb[34]; XR[3] = xb[35];

  for (int t = 0; t < 512; ++t) {
    // ---- poll (all waves; 8 flags in one 64B line) + stage h(t-1)
    if (t > 0) {
      int iters = 0;
      while (true) {
        unsigned v = (lane < 8) ? AL(&flags[g * 16 + lane]) : (unsigned)t;
        if (__ballot(v >= (unsigned)t) == ~0ull) break;
        if (++iters > (1 << 17)) break;   // valve: garbage instead of hang
        __builtin_amdgcn_s_sleep(1);
      }
      const unsigned long long* hp = (const unsigned long long*)h_all +
          ((size_t)(t - 1) * 256 + b0 + srow) * 64 + sseg * 8;
      H8U c0, c1, c2, c3;
      c0.u[0] = AL(hp + 0); c0.u[1] = AL(hp + 1);
      c1.u[0] = AL(hp + 2); c1.u[1] = AL(hp + 3);
      c2.u[0] = AL(hp + 4); c2.u[1] = AL(hp + 5);
      c3.u[0] = AL(hp + 6); c3.u[1] = AL(hp + 7);
      int hb = (s_rt * 12 + 4 + sseg) * 64 + s_lrow;
      ((half8*)At)[hb +  0] = c0.v; ((half8*)At)[hb + 16] = c1.v;
      ((half8*)At)[hb + 32] = c2.v; ((half8*)At)[hb + 48] = c3.v;
    } else {
      H8U zz; zz.u[0] = 0ull; zz.u[1] = 0ull;
      int hb = (s_rt * 12 + 4 + sseg) * 64 + s_lrow;
      ((half8*)At)[hb +  0] = zz.v; ((half8*)At)[hb + 16] = zz.v;
      ((half8*)At)[hb + 32] = zz.v; ((half8*)At)[hb + 48] = zz.v;
    }
    __syncthreads();   // B1: h frags ready

    // ---- h-part MFMA on top of precomputed x-part
    {
      f32x4 a0 = accx0, a1 = accx1, a2 = accx2, a3 = accx3;
      #pragma unroll
      for (int ks = 4; ks < 12; ++ks) {
        half8 av = Ap[ks * 64];
        a0 = __builtin_amdgcn_mfma_f32_16x16x32_f16(av, Bv[0 * 12 + ks], a0, 0, 0, 0);
        a1 = __builtin_amdgcn_mfma_f32_16x16x32_f16(av, Bv[1 * 12 + ks], a1, 0, 0, 0);
        a2 = __builtin_amdgcn_mfma_f32_16x16x32_f16(av, Bv[2 * 12 + ks], a2, 0, 0, 0);
        a3 = __builtin_amdgcn_mfma_f32_16x16x32_f16(av, Bv[3 * 12 + ks], a3, 0, 0, 0);
      }
      #pragma unroll
      for (int r = 0; r < 4; ++r) {
        pre_s[prow + r][(c4 + 0) * 16 + pc] = a0[r];
        pre_s[prow + r][(c4 + 1) * 16 + pc] = a1[r];
        pre_s[prow + r][(c4 + 2) * 16 + pc] = a2[r];
        pre_s[prow + r][(c4 + 3) * 16 + pc] = a3[r];
      }
    }
    __syncthreads();   // B2: gates ready

    // ---- elementwise LSTM update: 4 (row, d) items per thread
    #pragma unroll
    for (int ii = 0; ii < 4; ++ii) {
      int d = sseg + 8 * ii;
      float iv = fast_sigmoid(pre_s[srow][d]      + bias_s[d]);
      float fv = fast_sigmoid(pre_s[srow][32 + d] + bias_s[32 + d]);
      float gv = fast_tanh   (pre_s[srow][64 + d] + bias_s[64 + d]);
      float ov = fast_sigmoid(pre_s[srow][96 + d] + bias_s[96 + d]);
      float cv = fv * c_s[srow][d] + iv * gv;
      c_s[srow][d] = cv;
      h_s[srow][d] = (_Float16)(ov * fast_tanh(cv));
    }
    __syncthreads();   // B3: h_s ready

    // ---- coalesced 8B agent stores of h(t): one u64 per thread
    {
      unsigned long long hv = ((const unsigned long long*)h_s)[tid];
      unsigned long long* hp = (unsigned long long*)h_all +
          ((size_t)t * 256 + b0 + (tid >> 3)) * 64 + j * 8 + (tid & 7);
      __hip_atomic_store(hp, hv, __ATOMIC_RELAXED, __HIP_MEMORY_SCOPE_AGENT);
    }
    __syncthreads();   // B4: every wave drained its stores (vmcnt before barrier)

    if (tid == 0)
      __hip_atomic_store(&flags[g * 16 + j], (unsigned)(t + 1),
                         __ATOMIC_RELEASE, __HIP_MEMORY_SCOPE_AGENT);

    // ---- tail (off critical path): stage x(t+1), x-part MFMA, prefetch x(t+2)
    if (t < 511) {
      {
        half8 p0, p1;
        p0[0] = (_Float16)XR[0].x; p0[1] = (_Float16)XR[0].y;
        p0[2] = (_Float16)XR[0].z; p0[3] = (_Float16)XR[0].w;
        p0[4] = (_Float16)XR[1].x; p0[5] = (_Float16)XR[1].y;
        p0[6] = (_Float16)XR[1].z; p0[7] = (_Float16)XR[1].w;
        p1[0] = (_Float16)XR[2].x; p1[1] = (_Float16)XR[2].y;
        p1[2] = (_Float16)XR[2].z; p1[3] = (_Float16)XR[2].w;
        p1[4] = (_Float16)XR[3].x; p1[5] = (_Float16)XR[3].y;
        p1[6] = (_Float16)XR[3].z; p1[7] = (_Float16)XR[3].w;
        int xi = (s_rt * 12 + (sseg >> 1)) * 64 + ((sseg & 1) * 2) * 16 + s_lrow;
        ((half8*)At)[xi] = p0; ((half8*)At)[xi + 16] = p1;
      }
      __syncthreads();   // B5: x frags ready
      {
        accx0 = (f32x4){0.f, 0.f, 0.f, 0.f}; accx1 = accx0; accx2 = accx0; accx3 = accx0;
        #pragma unroll
        for (int ks = 0; ks < 4; ++ks) {
          half8 av = Ap[ks * 64];
          accx0 = __builtin_amdgcn_mfma_f32_16x16x32_f16(av, Bv[0 * 12 + ks], accx0, 0, 0, 0);
          accx1 = __builtin_amdgcn_mfma_f32_16x16x32_f16(av, Bv[1 * 12 + ks], accx1, 0, 0, 0);
          accx2 = __builtin_amdgcn_mfma_f32_16x16x32_f16(av, Bv[2 * 12 + ks], accx2, 0, 0, 0);
          accx3 = __builtin_amdgcn_mfma_f32_16x16x32_f16(av, Bv[3 * 12 + ks], accx3, 0, 0, 0);
        }
      }
      int tn = (t + 2 < 512) ? (t + 2) : 511;
      XR[0] = xb[(size_t)tn * 32 + 0]; XR[1] = xb[(size_t)tn * 32 + 1];
      XR[2] = xb[(size_t)tn * 32 + 2]; XR[3] = xb[(size_t)tn * 32 + 3];
    }
  }
}

// ---------------------------------------------------------------------------
// Head: per WG 64 rows of [T*B, H]; fused GEMM1->tanh->GEMM2->tanh->dot(W3).
// ---------------------------------------------------------------------------
__device__ __forceinline__ void head_gemm(const _Float16* __restrict__ A,
                                          const _Float16* __restrict__ Wf,
                                          const float* __restrict__ bvec,
                                          _Float16* __restrict__ Yd,
                                          int lane, int w)
{
  const half8* Af = (const half8*)A + w * 512 + lane;
  for (int ct = 0; ct < 16; ++ct) {
    const half8* Bf = (const half8*)Wf + ct * 512 + lane;
    f32x4 acc = {0.f, 0.f, 0.f, 0.f};
    #pragma unroll
    for (int ks = 0; ks < 8; ++ks)
      acc = __builtin_amdgcn_mfma_f32_16x16x32_f16(Af[ks * 64], Bf[ks * 64], acc, 0, 0, 0);
    int col = ct * 16 + (lane & 15);
    float bb = bvec[col];
    int ks2 = col >> 5, kg2 = (col >> 3) & 3, s2 = col & 7;
    #pragma unroll
    for (int r = 0; r < 4; ++r) {
      int row = w * 16 + ((lane >> 4) << 2) + r;
      float v = fast_tanh(acc[r] + bb);
      Yd[(((w * 8 + ks2) * 64) + kg2 * 16 + (row & 15)) * 8 + s2] = (_Float16)v;
    }
  }
}

__global__ void __launch_bounds__(256) head_kernel(
    const _Float16* __restrict__ h_all,
    const _Float16* __restrict__ W1f, const _Float16* __restrict__ W2f,
    const float* __restrict__ b1, const float* __restrict__ b2,
    const float* __restrict__ W3, const float* __restrict__ b3,
    float* __restrict__ out)
{
  __shared__ __align__(16) _Float16 A_s[16384];   // 32 KB
  __shared__ __align__(16) _Float16 Y_s[16384];   // 32 KB
  const int tid = threadIdx.x;
  const size_t r0 = (size_t)blockIdx.x * 64;

  {
    int row = tid >> 2, seg = tid & 3;
    int rtl = row >> 4, lrow = row & 15;
    const half8* hp = (const half8*)(h_all + (r0 + row) * 256 + seg * 64);
    #pragma unroll
    for (int i = 0; i < 8; ++i) {
      int k0 = seg * 64 + i * 8;
      int ks = k0 >> 5, kg = (k0 >> 3) & 3;
      ((half8*)A_s)[(rtl * 8 + ks) * 64 + kg * 16 + lrow] = hp[i];
    }
  }
  __syncthreads();

  const int lane = tid & 63, w = tid >> 6;
  head_gemm(A_s, W1f, b1, Y_s, lane, w);   // y1 = tanh(h @ W1 + b1)
  __syncthreads();
  head_gemm(Y_s, W2f, b2, A_s, lane, w);   // y2 = tanh(y1 @ W2 + b2)
  __syncthreads();

  {
    int row = tid >> 2, part = tid & 3;
    int rtl = row >> 4, lrow = row & 15;
    float p = 0.f;
    #pragma unroll
    for (int kk = 0; kk < 8; ++kk) {
      int k0 = part * 64 + kk * 8;
      int ks = k0 >> 5, kg = (k0 >> 3) & 3;
      half8 y = ((const half8*)A_s)[(rtl * 8 + ks) * 64 + kg * 16 + lrow];
      #pragma unroll
      for (int i = 0; i < 8; ++i) p += (float)y[i] * W3[k0 + i];
    }
    p += __shfl_xor(p, 1);
    p += __shfl_xor(p, 2);
    if (part == 0) {
      size_t r = r0 + row;                 // r = t*256 + b
      int tt = (int)(r >> 8), bb = (int)(r & 255);
      out[(size_t)bb * 512 + tt] = p + b3[0];
    }
  }
}

// ---------------------------------------------------------------------------
extern "C" void kernel_launch(void* const* d_in, const int* in_sizes, int n_in,
                              void* d_out, int out_size, void* d_ws, size_t ws_size,
                              hipStream_t stream)
{
  const float* x  = (const float*)d_in[0];
  const float* Wx = (const float*)d_in[1];
  const float* Wh = (const float*)d_in[2];
  const float* b  = (const float*)d_in[3];
  const float* W1 = (const float*)d_in[4];
  const float* b1 = (const float*)d_in[5];
  const float* W2 = (const float*)d_in[6];
  const float* b2 = (const float*)d_in[7];
  const float* W3 = (const float*)d_in[8];
  const float* b3 = (const float*)d_in[9];
  float* out = (float*)d_out;

  char* ws = (char*)d_ws;
  unsigned* flags  = (unsigned*)ws;                       // 128 u32 used (pad to 4 KB)
  _Float16* W1f    = (_Float16*)(ws + 4096);              // 128 KB
  _Float16* W2f    = (_Float16*)(ws + 4096 + 131072);     // 128 KB
  _Float16* h_all  = (_Float16*)(ws + 4096 + 262144);     // [512][256][256] f16 = 64 MB
  if (ws_size < (size_t)4096 + 262144 + 67108864) return; // insufficient scratch

  hipLaunchKernelGGL(prep_kernel, dim3(512), dim3(256), 0, stream,
                     W1, W2, W1f, W2f, flags);
  hipLaunchKernelGGL(lstm_rec_kernel, dim3(64), dim3(256), 0, stream,
                     x, Wx, Wh, b, h_all, flags);
  hipLaunchKernelGGL(head_kernel, dim3(2048), dim3(256), 0, stream,
                     h_all, W1f, W2f, b1, b2, W3, b3, out);
}